// Round 17
// baseline (119.680 us; speedup 1.0000x reference)
//
#include <hip/hip_runtime.h>
#include <stdint.h>

typedef __attribute__((ext_vector_type(8))) short short8;
typedef __attribute__((ext_vector_type(4))) short short4v;
typedef __attribute__((ext_vector_type(4))) float floatx4;
typedef __attribute__((ext_vector_type(16))) float floatx16;

#define B_ 2
#define L_ 2048
#define C_ 1024
#define H_ 16
#define HD_ 64

// Q scale: 1/64 (both ref scales) * log2(e) so softmax exp becomes exp2 directly.
#define QSCALE (0.015625f * 1.44269504088896f)
// masked score addend in log2-units: -1.25e9 * log2e. exp2 -> exactly 0 (bf16-rounded too).
#define MASKVAL (-1.8033688e9f)

__device__ __forceinline__ unsigned short f2bf(float f) {
  union { float f; uint32_t u; } v; v.f = f;
  uint32_t r = 0x7FFFu + ((v.u >> 16) & 1u);
  return (unsigned short)((v.u + r) >> 16);
}

__device__ __forceinline__ uint32_t cvtpk(float lo, float hi) {
  uint32_t r;
  asm("v_cvt_pk_bf16_f32 %0, %1, %2" : "=v"(r) : "v"(lo), "v"(hi));
  return r;
}

// hardware pack f32->bf16 (bias-insensitive intermediate paths only — R9 lesson)
__device__ __forceinline__ unsigned short f2bf_hw(float f) {
  return (unsigned short)cvtpk(f, f);
}

// vdst[32:63] <-> vsrc[0:31]
__device__ __forceinline__ void pl32swap(uint32_t& a, uint32_t& b) {
  asm volatile("v_permlane32_swap_b32 %0, %1" : "+v"(a), "+v"(b));
}

__device__ __forceinline__ void async16(const void* g, void* l) {
  __builtin_amdgcn_global_load_lds(
      (const __attribute__((address_space(1))) void*)g,
      (__attribute__((address_space(3))) void*)l, 16, 0, 0);
}

// -------- fused prep: x f32->bf16 cast (blocks 0..2047) + mask precompute (2048..) --------
__global__ __launch_bounds__(256) void prep_k(const float* __restrict__ x,
                                              unsigned short* __restrict__ Xb,
                                              const int* __restrict__ mask,
                                              unsigned short* __restrict__ maskbf) {
  int bid = blockIdx.x;
  if (bid < 2048) {
    int i = (bid * 256 + threadIdx.x) * 8;
    floatx4 a = *(const floatx4*)(x + i);
    floatx4 b = *(const floatx4*)(x + i + 4);
    short8 o;
    o[0] = (short)f2bf(a[0]); o[1] = (short)f2bf(a[1]);
    o[2] = (short)f2bf(a[2]); o[3] = (short)f2bf(a[3]);
    o[4] = (short)f2bf(b[0]); o[5] = (short)f2bf(b[1]);
    o[6] = (short)f2bf(b[2]); o[7] = (short)f2bf(b[3]);
    *(short8*)(Xb + i) = o;
  } else if (maskbf) {
    int i = (bid - 2048) * 256 + threadIdx.x;
    if (i < B_ * L_) maskbf[i] = (mask[i] == 1) ? f2bf(MASKVAL) : (unsigned short)0;
  }
}

// -------- mask precompute fallback (if ws too small for fused placement) --------
__global__ __launch_bounds__(256) void maskpre_k(const int* __restrict__ mask,
                                                 unsigned short* __restrict__ maskbf) {
  int i = blockIdx.x * 256 + threadIdx.x;
  if (i < B_ * L_) maskbf[i] = (mask[i] == 1) ? f2bf(MASKVAL) : (unsigned short)0;
}

// -------- fused transpose+cast for both weights: z=0 Wqkv [C][3C], z=1 Wproj [C][C] --------
__global__ __launch_bounds__(256) void transpose2_k(const float* __restrict__ W1,
                                                    unsigned short* __restrict__ O1,
                                                    const float* __restrict__ W2,
                                                    unsigned short* __restrict__ O2) {
  const int z = blockIdx.z;
  if (z == 1 && blockIdx.x >= C_ / 32) return;
  const float* in = z ? W2 : W1;
  unsigned short* out = z ? O2 : O1;
  const int Cc = z ? C_ : 3 * C_;
  __shared__ float tile[32][33];
  int tx = threadIdx.x, ty = threadIdx.y;
  int c0 = blockIdx.x * 32, r0 = blockIdx.y * 32;
#pragma unroll
  for (int i = 0; i < 4; i++)
    tile[ty + i * 8][tx] = in[(r0 + ty + i * 8) * Cc + c0 + tx];
  __syncthreads();
#pragma unroll
  for (int i = 0; i < 4; i++)
    out[(c0 + ty + i * 8) * C_ + r0 + tx] = f2bf(tile[tx][ty + i * 8]);
}

// -------- 128xBNx(BK=32) bf16 MFMA GEMM, double-buffered 2-phase --------
// A [M][K], BT [N][K] row-major. 1-D grid, bijective XCD swizzle (nwg % 8 == 0).
// EPI 1 (BN=128): QKV epilogue (block-uniform which: col tiles 0-7=Q, 8-15=K, 16-23=VT).
// EPI 2 (BN=64): proj epilogue (bias, fp32 out); 512 blocks = 2/CU (TLP).
template <int EPI, int BN>
__global__ __launch_bounds__(256) void gemm128(const unsigned short* __restrict__ A,
                                               const unsigned short* __restrict__ BT, int K,
                                               int nbx,
                                               const float* __restrict__ bias,
                                               unsigned short* __restrict__ outQ,
                                               unsigned short* __restrict__ outK,
                                               unsigned short* __restrict__ outVT,
                                               float* __restrict__ outF) {
  __shared__ __attribute__((aligned(16))) unsigned short Asmem[2][128 * 32];
  __shared__ __attribute__((aligned(16))) unsigned short Bsmem[2][BN * 32];
  const int t = threadIdx.x;
  const int wave = t >> 6, lane = t & 63;
  const int wr = wave >> 1, wc = wave & 1;
  const int NW = BN / 2;   // cols per wave
  const int NF = BN / 32;  // 16x16 col-frags per wave
  const int nwg = gridDim.x;
  const int id = (blockIdx.x & 7) * (nwg >> 3) + (blockIdx.x >> 3);
  const int bx = id % nbx, by = id / nbx;
  const int row0 = by * 128, col0 = bx * BN;

  const int arow = row0 + (t >> 2), brow = col0 + (t >> 2);
  const int koff = (t & 3) * 8;

#define STAGE(buf, k0)                                                                 \
  {                                                                                    \
    async16(A + (size_t)arow * K + (k0) + koff, &Asmem[buf][t * 8]);                   \
    async16(A + (size_t)(arow + 64) * K + (k0) + koff, &Asmem[buf][(256 + t) * 8]);    \
    async16(BT + (size_t)brow * K + (k0) + koff, &Bsmem[buf][t * 8]);                  \
    if (BN == 128)                                                                     \
      async16(BT + (size_t)(brow + 64) * K + (k0) + koff, &Bsmem[buf][(256 + t) * 8]); \
  }

  floatx4 acc[4][NF] = {};
  STAGE(0, 0);
  __syncthreads();  // prologue drain
  int cur = 0;
  for (int k0 = 0; k0 < K; k0 += 32) {
    if (k0 + 32 < K) STAGE(cur ^ 1, k0 + 32);  // prefetch next tile (overlaps compute)
    short8 af[4], bfr[NF];
#pragma unroll
    for (int m = 0; m < 4; m++)
      af[m] = *(const short8*)(&Asmem[cur][(wr * 64 + m * 16 + (lane & 15)) * 32 +
                                           (lane >> 4) * 8]);
#pragma unroll
    for (int n = 0; n < NF; n++)
      bfr[n] = *(const short8*)(&Bsmem[cur][(wc * NW + n * 16 + (lane & 15)) * 32 +
                                            (lane >> 4) * 8]);
#pragma unroll
    for (int m = 0; m < 4; m++)
#pragma unroll
      for (int n = 0; n < NF; n++)
        acc[m][n] = __builtin_amdgcn_mfma_f32_16x16x32_bf16(af[m], bfr[n], acc[m][n], 0, 0, 0);
    __syncthreads();  // vmcnt(0) drain of prefetch + barrier
    cur ^= 1;
  }
#undef STAGE

#pragma unroll
  for (int m = 0; m < 4; m++)
#pragma unroll
    for (int n = 0; n < NF; n++) {
      const int r0e = row0 + wr * 64 + m * 16 + (lane >> 4) * 4;
      const int cc = col0 + wc * NW + n * 16 + (lane & 15);
      const float bv = bias[cc];
      if (EPI == 2) {
#pragma unroll
        for (int j = 0; j < 4; j++)
          outF[(size_t)(r0e + j) * C_ + cc] = acc[m][n][j] + bv;
      } else {
        const int which = col0 >> 10;  // block-uniform
        const int rem = cc & 1023, h = rem >> 6, d = rem & 63;
        const int bb = r0e >> 11, l0 = r0e & 2047;
        const size_t base = (size_t)(bb * H_ + h) * (L_ * HD_);
        if (which == 0) {
#pragma unroll
          for (int j = 0; j < 4; j++)
            outQ[base + (size_t)(l0 + j) * HD_ + d] = f2bf_hw((acc[m][n][j] + bv) * QSCALE);
        } else if (which == 1) {
          const size_t kbase =
              base + ((l0 >> 5) * 8 + (d >> 4) * 2 + ((d >> 3) & 1)) * 256 + (d & 7);
#pragma unroll
          for (int j = 0; j < 4; j++)
            outK[kbase + ((l0 & 31) + j) * 8] = f2bf_hw(acc[m][n][j] + bv);
        } else {
          const size_t vbase = base +
                               ((((l0 >> 7) * 2 + (d >> 5)) * 8 + ((l0 >> 4) & 7)) * 2 +
                                ((l0 >> 3) & 1)) * 256 +
                               (d & 31) * 8 + (l0 & 7);
          union { unsigned short s[4]; short4v v; } ov;
#pragma unroll
          for (int j = 0; j < 4; j++) ov.s[j] = f2bf_hw(acc[m][n][j] + bv);
          *(short4v*)(outVT + vbase) = ov.v;
        }
      }
    }
}

// -------- flash attention, 32x32x16 MFMA, swapped-operand, register P --------
// R17: split-KV across wave-groups. 8 waves (512 thr), QBLK=128:
//   waves 0-3 (half 0) process kv tiles 0-7; waves 4-7 (half 1) kv tiles 8-15.
// Per step the block stages a tile PAIR (one per half): total staged bytes/block
// unchanged vs R16, per-thread staging halved, barriers halved (8 steps), and
// waves/CU doubles to 16 (LDS 68KB -> 2 blocks/CU). Fixed-max-0 softmax makes
// halves combine exactly: o = o0+o1, l = l0+l1 (LDS merge in epilogue, no extra ws).
// Per-half numeric path identical to R16 (mask rank-1 MFMA, tree rs, cvt_pk+permlane).
__global__ __launch_bounds__(512) void attn_k(const unsigned short* __restrict__ Q,
                                              const unsigned short* __restrict__ Kf,
                                              const unsigned short* __restrict__ VTf,
                                              const unsigned short* __restrict__ maskbf,
                                              unsigned short* __restrict__ attn_out) {
  __shared__ __attribute__((aligned(16))) unsigned short Ks[2 * 128 * 64];   // [half][8192]
  __shared__ __attribute__((aligned(16))) unsigned short VTs[2 * 64 * 128];  // [half][8192]
  __shared__ __attribute__((aligned(16))) unsigned short maskLb[L_];         // bf16 addend

  const int t = threadIdx.x, wave = t >> 6, lane = t & 63;
  const int h = lane >> 5, c32 = lane & 31;
  const int half = wave >> 2, wq = wave & 3;
  // id = qt*32 + bh -> all q-tiles of a head share an XCD (K/V L2 reuse).
  const int bh = blockIdx.x & 31;
  const int qt = blockIdx.x >> 5;
  const int b = bh >> 4, hh = bh & 15;
  const unsigned short* Qp = Q + (size_t)bh * L_ * HD_;
  const unsigned short* Kp = Kf + (size_t)bh * L_ * HD_;
  const unsigned short* VTp = VTf + (size_t)bh * L_ * HD_;
  const int qrow = qt * 128 + wq * 32 + c32;

  // Q B-fragments from global: lane holds Q[q=qrow][d = ks*16 + h*8 + r]
  short8 qf[4];
#pragma unroll
  for (int ks = 0; ks < 4; ks++)
    qf[ks] = *(const short8*)(Qp + (size_t)qrow * HD_ + ks * 16 + h * 8);

  // ones row-fragment for the mask MFMA: B[0][q] = 1.0 (bf16 0x3F80), else 0
  union { uint32_t u[4]; short8 v; } onef;
  onef.u[0] = h ? 0u : 0x3F80u;
  onef.u[1] = 0; onef.u[2] = 0; onef.u[3] = 0;
  floatx16 z16;
#pragma unroll
  for (int e = 0; e < 16; e++) z16[e] = 0.f;

  // stage bf16 mask addend once (256 chunks over 512 threads)
  if (t < 256) async16(maskbf + b * L_ + t * 8, maskLb + t * 8);

  floatx16 o[2] = {};  // O^T acc, dg = 0,1
  float lrun = 0.f;

  const unsigned short* KsW = Ks + half * 8192;
  const unsigned short* VTsW = VTs + half * 8192;

  for (int step = 0; step < 8; step++) {
    __syncthreads();  // prev step's reads done (and first-iter mask staged)
    // stage tile pair: idx<1024 -> half0 tile (kv=step), idx>=1024 -> half1 (kv=step+8)
    // 64-aligned wave chunks never straddle the 1024 boundary -> coalesced per wave.
#pragma unroll
    for (int i = 0; i < 4; i++) {
      int idx = i * 512 + t, hf = idx >> 10, off = idx & 1023;
      async16(Kp + (size_t)(step + 8 * hf) * 8192 + off * 8, Ks + idx * 8);
    }
#pragma unroll
    for (int i = 0; i < 4; i++) {
      int idx = i * 512 + t, hf = idx >> 10, off = idx & 1023;
      async16(VTp + (size_t)(step + 8 * hf) * 8192 + off * 8, VTs + idx * 8);
    }
    __syncthreads();  // vmcnt drained: both tiles visible

    const int moff = (step + 8 * half) * 128;

    // ---- S^T = mask⊗1 + K Q^T (mask enters as rank-1 MFMA, C = zero16) ----
    floatx16 s[4];
#pragma unroll
    for (int kg = 0; kg < 4; kg++) {
      union { uint32_t u[4]; short8 v; } mf;
      unsigned short mval = maskLb[moff + kg * 32 + c32];
      mf.u[0] = h ? 0u : (uint32_t)mval;
      mf.u[1] = 0; mf.u[2] = 0; mf.u[3] = 0;
      s[kg] = __builtin_amdgcn_mfma_f32_32x32x16_bf16(mf.v, onef.v, z16, 0, 0, 0);
#pragma unroll
      for (int ks = 0; ks < 4; ks++) {
        const short8 kfr = *(const short8*)(KsW + ((kg * 4 + ks) * 2 + h) * 256 + c32 * 8);
        s[kg] = __builtin_amdgcn_mfma_f32_32x32x16_bf16(kfr, qf[ks], s[kg], 0, 0, 0);
      }
    }

    // ---- softmax (fixed max 0): p = exp2(s); tree rowsum (4 chains) + lane^32 ----
    float r0 = 0.f, r1 = 0.f, r2 = 0.f, r3 = 0.f;
#pragma unroll
    for (int kg = 0; kg < 4; kg++)
#pragma unroll
      for (int q = 0; q < 4; q++) {
        float p0 = __builtin_amdgcn_exp2f(s[kg][4 * q + 0]);
        float p1 = __builtin_amdgcn_exp2f(s[kg][4 * q + 1]);
        float p2 = __builtin_amdgcn_exp2f(s[kg][4 * q + 2]);
        float p3 = __builtin_amdgcn_exp2f(s[kg][4 * q + 3]);
        s[kg][4 * q + 0] = p0; s[kg][4 * q + 1] = p1;
        s[kg][4 * q + 2] = p2; s[kg][4 * q + 3] = p3;
        r0 += p0; r1 += p1; r2 += p2; r3 += p3;
      }
    float rs = (r0 + r1) + (r2 + r3);
    rs += __shfl_xor(rs, 32);
    lrun += rs;

    // ---- P -> B-fragments (cvt_pk + permlane32_swap), O^T += VT * P^T ----
#pragma unroll
    for (int kg = 0; kg < 4; kg++) {
      uint32_t pk[8];
#pragma unroll
      for (int e = 0; e < 8; e++) pk[e] = cvtpk(s[kg][2 * e], s[kg][2 * e + 1]);
      // pk[e]: rr = e>>1, p = e&1; keys kg*32 + 8rr + 4h + 2p + {0,1}
#pragma unroll
      for (int ts = 0; ts < 2; ts++) {
        uint32_t x0 = pk[4 * ts + 0], x1 = pk[4 * ts + 1];      // rr = 2ts
        uint32_t y0 = pk[4 * ts + 2], y1 = pk[4 * ts + 3];      // rr = 2ts+1
        pl32swap(x0, y0);  // now lane h gets rr=2ts+h: x=(hs0), y=(hs1)
        pl32swap(x1, y1);
        union { uint32_t u[4]; short8 v; } pf;
        pf.u[0] = x0; pf.u[1] = x1; pf.u[2] = y0; pf.u[3] = y1;
        const int kt = kg * 2 + ts;
#pragma unroll
        for (int dg = 0; dg < 2; dg++) {
          const short8 vfr =
              *(const short8*)(VTsW + ((dg * 8 + kt) * 2 + h) * 256 + c32 * 8);
          o[dg] = __builtin_amdgcn_mfma_f32_32x32x16_bf16(vfr, pf.v, o[dg], 0, 0, 0);
        }
      }
    }
  }

  // ---- merge halves via LDS (reuse Ks as f32 Os[128][64], VTs as Ls[128]) ----
  __syncthreads();  // all waves done reading Ks/VTs
  float* Os = (float*)Ks;
  float* Ls = (float*)VTs;
  const int qlocal = wq * 32 + c32;
  if (half == 1) {
#pragma unroll
    for (int dg = 0; dg < 2; dg++)
#pragma unroll
      for (int rr = 0; rr < 4; rr++) {
        floatx4 q4;
#pragma unroll
        for (int jj = 0; jj < 4; jj++) q4[jj] = o[dg][rr * 4 + jj];
        *(floatx4*)(Os + qlocal * 64 + dg * 32 + rr * 8 + h * 4) = q4;
      }
    if (h == 0) Ls[qlocal] = lrun;
  }
  __syncthreads();
  if (half == 0) {
    const float inv = 1.f / (lrun + Ls[qlocal]);
#pragma unroll
    for (int dg = 0; dg < 2; dg++)
#pragma unroll
      for (int rr = 0; rr < 4; rr++) {
        const int d0 = dg * 32 + rr * 8 + h * 4;
        floatx4 q4 = *(const floatx4*)(Os + qlocal * 64 + d0);
        short4v ov;
#pragma unroll
        for (int jj = 0; jj < 4; jj++)
          ov[jj] = (short)f2bf((o[dg][rr * 4 + jj] + q4[jj]) * inv);
        *(short4v*)(attn_out + ((size_t)b * L_ + qrow) * C_ + hh * HD_ + d0) = ov;
      }
  }
}

extern "C" void kernel_launch(void* const* d_in, const int* in_sizes, int n_in,
                              void* d_out, int out_size, void* d_ws, size_t ws_size,
                              hipStream_t stream) {
  const float* x = (const float*)d_in[0];
  const int* mask = (const int*)d_in[1];
  const float* Wqkv = (const float*)d_in[2];
  const float* bqkv = (const float*)d_in[3];
  const float* Wproj = (const float*)d_in[4];
  const float* bproj = (const float*)d_in[5];
  float* out = (float*)d_out;
  char* ws = (char*)d_ws;

  unsigned short* Xb = (unsigned short*)(ws);                    // 8 MB [4096][1024]
  unsigned short* WqkvT = (unsigned short*)(ws + (8u << 20));    // 6 MB [3072][1024]
  unsigned short* WprojT = (unsigned short*)(ws + (14u << 20));  // 2 MB [1024][1024]
  unsigned short* Qb = (unsigned short*)(ws + (16u << 20));      // 8 MB [32][2048][64]
  unsigned short* Kb = (unsigned short*)(ws + (24u << 20));      // 8 MB frag-order
  unsigned short* VTb = (unsigned short*)(ws + (32u << 20));     // 8 MB frag-order
  unsigned short* AOb = Xb;                                      // reuse (Xb dead after gemm1)

  // maskbf: prefer fresh 8KB at 40MB (enables fusing into prep_k); else reuse
  // WqkvT region and fill it AFTER gemm1 (fallback ordering).
  const bool fused_mask = ws_size >= ((size_t)(40u << 20) + 8192);
  unsigned short* maskbf = fused_mask ? (unsigned short*)(ws + (40u << 20))
                                      : (unsigned short*)(ws + (8u << 20));

  prep_k<<<2064, 256, 0, stream>>>(x, Xb, mask, fused_mask ? maskbf : nullptr);

  dim3 tb(32, 8);
  transpose2_k<<<dim3(3 * C_ / 32, C_ / 32, 2), tb, 0, stream>>>(Wqkv, WqkvT, Wproj, WprojT);

  gemm128<1, 128><<<768, 256, 0, stream>>>(Xb, WqkvT, C_, 24, bqkv, Qb, Kb, VTb, nullptr);

  if (!fused_mask) maskpre_k<<<(B_ * L_) / 256, 256, 0, stream>>>(mask, maskbf);

  attn_k<<<B_ * H_ * (L_ / 128), 512, 0, stream>>>(Qb, Kb, VTb, maskbf, AOb);

  gemm128<2, 64><<<512, 256, 0, stream>>>(AOb, WprojT, C_, 16, bproj, nullptr, nullptr, nullptr,
                                          out);
}

// Round 19
// 110.269 us; speedup vs baseline: 1.0853x; 1.0853x over previous
//
#include <hip/hip_runtime.h>
#include <stdint.h>

typedef __attribute__((ext_vector_type(8))) short short8;
typedef __attribute__((ext_vector_type(4))) short short4v;
typedef __attribute__((ext_vector_type(4))) float floatx4;
typedef __attribute__((ext_vector_type(16))) float floatx16;

#define B_ 2
#define L_ 2048
#define C_ 1024
#define H_ 16
#define HD_ 64

// Q scale: 1/64 (both ref scales) * log2(e) so softmax exp becomes exp2 directly.
#define QSCALE (0.015625f * 1.44269504088896f)
// masked score addend in log2-units: -1.25e9 * log2e. exp2 -> exactly 0 (bf16-rounded too).
#define MASKVAL (-1.8033688e9f)

__device__ __forceinline__ unsigned short f2bf(float f) {
  union { float f; uint32_t u; } v; v.f = f;
  uint32_t r = 0x7FFFu + ((v.u >> 16) & 1u);
  return (unsigned short)((v.u + r) >> 16);
}

__device__ __forceinline__ uint32_t cvtpk(float lo, float hi) {
  uint32_t r;
  asm("v_cvt_pk_bf16_f32 %0, %1, %2" : "=v"(r) : "v"(lo), "v"(hi));
  return r;
}

// hardware pack f32->bf16 (bias-insensitive intermediate paths only — R9 lesson)
__device__ __forceinline__ unsigned short f2bf_hw(float f) {
  return (unsigned short)cvtpk(f, f);
}

// vdst[32:63] <-> vsrc[0:31]
__device__ __forceinline__ void pl32swap(uint32_t& a, uint32_t& b) {
  asm volatile("v_permlane32_swap_b32 %0, %1" : "+v"(a), "+v"(b));
}

__device__ __forceinline__ void async16(const void* g, void* l) {
  __builtin_amdgcn_global_load_lds(
      (const __attribute__((address_space(1))) void*)g,
      (__attribute__((address_space(3))) void*)l, 16, 0, 0);
}

// -------- fully fused prep (ONE launch):
//   blocks [0, 2048)        : x f32->bf16 cast (8 elems/thread)
//   blocks [2048, 2064)     : mask -> bf16 {0, MASKVAL}
//   blocks [2064, 5136)     : Wqkv transpose+cast tiles (96 x 32)
//   blocks [5136, 6160)     : Wproj transpose+cast tiles (32 x 32)
__global__ __launch_bounds__(256) void prep_k(const float* __restrict__ x,
                                              unsigned short* __restrict__ Xb,
                                              const int* __restrict__ mask,
                                              unsigned short* __restrict__ maskbf,
                                              const float* __restrict__ Wqkv,
                                              unsigned short* __restrict__ WqkvT,
                                              const float* __restrict__ Wproj,
                                              unsigned short* __restrict__ WprojT) {
  const int bid = blockIdx.x;
  const int t = threadIdx.x;
  if (bid < 2048) {
    int i = (bid * 256 + t) * 8;
    floatx4 a = *(const floatx4*)(x + i);
    floatx4 b = *(const floatx4*)(x + i + 4);
    short8 o;
    o[0] = (short)f2bf(a[0]); o[1] = (short)f2bf(a[1]);
    o[2] = (short)f2bf(a[2]); o[3] = (short)f2bf(a[3]);
    o[4] = (short)f2bf(b[0]); o[5] = (short)f2bf(b[1]);
    o[6] = (short)f2bf(b[2]); o[7] = (short)f2bf(b[3]);
    *(short8*)(Xb + i) = o;
    return;
  }
  if (bid < 2064) {
    int i = (bid - 2048) * 256 + t;
    if (i < B_ * L_) maskbf[i] = (mask[i] == 1) ? f2bf(MASKVAL) : (unsigned short)0;
    return;
  }
  // transpose tiles
  __shared__ float tile[32][33];
  int idx = bid - 2064;
  const float* in;
  unsigned short* out;
  int Cc, bx, by;
  if (idx < 3072) {            // Wqkv: [C][3C] -> [3C][C]
    in = Wqkv; out = WqkvT; Cc = 3 * C_;
    bx = idx % 96; by = idx / 96;
  } else {                     // Wproj: [C][C] -> [C][C]
    idx -= 3072;
    in = Wproj; out = WprojT; Cc = C_;
    bx = idx % 32; by = idx / 32;
  }
  const int tx = t & 31, ty = t >> 5;
  const int c0 = bx * 32, r0 = by * 32;
#pragma unroll
  for (int i = 0; i < 4; i++)
    tile[ty + i * 8][tx] = in[(r0 + ty + i * 8) * Cc + c0 + tx];
  __syncthreads();
#pragma unroll
  for (int i = 0; i < 4; i++)
    out[(c0 + ty + i * 8) * C_ + r0 + tx] = f2bf(tile[tx][ty + i * 8]);
}

// -------- 128xBNx(BK=32) bf16 MFMA GEMM, double-buffered 2-phase --------
// A [M][K], BT [N][K] row-major. 1-D grid, bijective XCD swizzle (nwg % 8 == 0).
// EPI 1 (BN=128): QKV epilogue (block-uniform which: col tiles 0-7=Q, 8-15=K, 16-23=VT).
// EPI 2 (BN=64): proj epilogue (bias, fp32 out); 512 blocks = 2/CU (TLP).
template <int EPI, int BN>
__global__ __launch_bounds__(256) void gemm128(const unsigned short* __restrict__ A,
                                               const unsigned short* __restrict__ BT, int K,
                                               int nbx,
                                               const float* __restrict__ bias,
                                               unsigned short* __restrict__ outQ,
                                               unsigned short* __restrict__ outK,
                                               unsigned short* __restrict__ outVT,
                                               float* __restrict__ outF) {
  __shared__ __attribute__((aligned(16))) unsigned short Asmem[2][128 * 32];
  __shared__ __attribute__((aligned(16))) unsigned short Bsmem[2][BN * 32];
  const int t = threadIdx.x;
  const int wave = t >> 6, lane = t & 63;
  const int wr = wave >> 1, wc = wave & 1;
  const int NW = BN / 2;   // cols per wave
  const int NF = BN / 32;  // 16x16 col-frags per wave
  const int nwg = gridDim.x;
  const int id = (blockIdx.x & 7) * (nwg >> 3) + (blockIdx.x >> 3);
  const int bx = id % nbx, by = id / nbx;
  const int row0 = by * 128, col0 = bx * BN;

  const int arow = row0 + (t >> 2), brow = col0 + (t >> 2);
  const int koff = (t & 3) * 8;

#define STAGE(buf, k0)                                                                 \
  {                                                                                    \
    async16(A + (size_t)arow * K + (k0) + koff, &Asmem[buf][t * 8]);                   \
    async16(A + (size_t)(arow + 64) * K + (k0) + koff, &Asmem[buf][(256 + t) * 8]);    \
    async16(BT + (size_t)brow * K + (k0) + koff, &Bsmem[buf][t * 8]);                  \
    if (BN == 128)                                                                     \
      async16(BT + (size_t)(brow + 64) * K + (k0) + koff, &Bsmem[buf][(256 + t) * 8]); \
  }

  floatx4 acc[4][NF] = {};
  STAGE(0, 0);
  __syncthreads();  // prologue drain
  int cur = 0;
  for (int k0 = 0; k0 < K; k0 += 32) {
    if (k0 + 32 < K) STAGE(cur ^ 1, k0 + 32);  // prefetch next tile (overlaps compute)
    short8 af[4], bfr[NF];
#pragma unroll
    for (int m = 0; m < 4; m++)
      af[m] = *(const short8*)(&Asmem[cur][(wr * 64 + m * 16 + (lane & 15)) * 32 +
                                           (lane >> 4) * 8]);
#pragma unroll
    for (int n = 0; n < NF; n++)
      bfr[n] = *(const short8*)(&Bsmem[cur][(wc * NW + n * 16 + (lane & 15)) * 32 +
                                            (lane >> 4) * 8]);
#pragma unroll
    for (int m = 0; m < 4; m++)
#pragma unroll
      for (int n = 0; n < NF; n++)
        acc[m][n] = __builtin_amdgcn_mfma_f32_16x16x32_bf16(af[m], bfr[n], acc[m][n], 0, 0, 0);
    __syncthreads();  // vmcnt(0) drain of prefetch + barrier
    cur ^= 1;
  }
#undef STAGE

#pragma unroll
  for (int m = 0; m < 4; m++)
#pragma unroll
    for (int n = 0; n < NF; n++) {
      const int r0e = row0 + wr * 64 + m * 16 + (lane >> 4) * 4;
      const int cc = col0 + wc * NW + n * 16 + (lane & 15);
      const float bv = bias[cc];
      if (EPI == 2) {
#pragma unroll
        for (int j = 0; j < 4; j++)
          outF[(size_t)(r0e + j) * C_ + cc] = acc[m][n][j] + bv;
      } else {
        const int which = col0 >> 10;  // block-uniform
        const int rem = cc & 1023, h = rem >> 6, d = rem & 63;
        const int bb = r0e >> 11, l0 = r0e & 2047;
        const size_t base = (size_t)(bb * H_ + h) * (L_ * HD_);
        if (which == 0) {
#pragma unroll
          for (int j = 0; j < 4; j++)
            outQ[base + (size_t)(l0 + j) * HD_ + d] = f2bf_hw((acc[m][n][j] + bv) * QSCALE);
        } else if (which == 1) {
          const size_t kbase =
              base + ((l0 >> 5) * 8 + (d >> 4) * 2 + ((d >> 3) & 1)) * 256 + (d & 7);
#pragma unroll
          for (int j = 0; j < 4; j++)
            outK[kbase + ((l0 & 31) + j) * 8] = f2bf_hw(acc[m][n][j] + bv);
        } else {
          const size_t vbase = base +
                               ((((l0 >> 7) * 2 + (d >> 5)) * 8 + ((l0 >> 4) & 7)) * 2 +
                                ((l0 >> 3) & 1)) * 256 +
                               (d & 31) * 8 + (l0 & 7);
          union { unsigned short s[4]; short4v v; } ov;
#pragma unroll
          for (int j = 0; j < 4; j++) ov.s[j] = f2bf_hw(acc[m][n][j] + bv);
          *(short4v*)(outVT + vbase) = ov.v;
        }
      }
    }
}

// -------- flash attention, 32x32x16 MFMA, swapped-operand, register P --------
// EXACT R16 kernel (best measured: ~53 us) — attn structure is FROZEN.
// Six restructures (dbuf, setprio, small blocks, counted-vmcnt, KVBLK=256,
// split-KV wave groups) all regressed; 2-block/CU TLP hides stage latency.
// 4 waves, wave = 32 q rows (q = lane&31), KV tile = 128, QBLK = 128.
// S^T = mfma(A=K_frag, B=Q_frag): lane(h,c32) holds S[key=kg*32+(e&3)+8*(e>>2)+4h][q=c32].
// Mask via rank-1 MFMA: s = mfma(mask_col_frag, ones_row_frag, zero16).
// P->B-frag redistribution: cvt_pk pairs + v_permlane32_swap_b32 (VALU pipe, no LDS).
// PV: O^T = mfma(A=VT_frag, B=P_frag): lane holds O[d=dg*32+(e&3)+8*(e>>2)+4h][q=c32].
__global__ __launch_bounds__(256) void attn_k(const unsigned short* __restrict__ Q,
                                              const unsigned short* __restrict__ Kf,
                                              const unsigned short* __restrict__ VTf,
                                              const unsigned short* __restrict__ maskbf,
                                              unsigned short* __restrict__ attn_out) {
  __shared__ __attribute__((aligned(16))) unsigned short Ks[128 * 64];   // frag-order, linear
  __shared__ __attribute__((aligned(16))) unsigned short VTs[64 * 128];  // frag-order, linear
  __shared__ __attribute__((aligned(16))) unsigned short maskLb[L_];     // bf16 mask addend

  const int t = threadIdx.x, wave = t >> 6, lane = t & 63;
  const int h = lane >> 5, c32 = lane & 31;
  // id = qt*32 + bh -> all q-tiles of a head share an XCD (K/V L2 reuse).
  const int bh = blockIdx.x & 31;
  const int qt = blockIdx.x >> 5;
  const int b = bh >> 4, hh = bh & 15;
  const unsigned short* Qp = Q + (size_t)bh * L_ * HD_;
  const unsigned short* Kp = Kf + (size_t)bh * L_ * HD_;
  const unsigned short* VTp = VTf + (size_t)bh * L_ * HD_;
  const int qrow = qt * 128 + wave * 32 + c32;

  // Q B-fragments from global: lane holds Q[q=qrow][d = ks*16 + h*8 + r]
  short8 qf[4];
#pragma unroll
  for (int ks = 0; ks < 4; ks++)
    qf[ks] = *(const short8*)(Qp + (size_t)qrow * HD_ + ks * 16 + h * 8);

  // ones row-fragment for the mask MFMA: B[0][q] = 1.0 (bf16 0x3F80), else 0
  union { uint32_t u[4]; short8 v; } onef;
  onef.u[0] = h ? 0u : 0x3F80u;
  onef.u[1] = 0; onef.u[2] = 0; onef.u[3] = 0;
  // persistent zero C-operand (init once; MFMA C and D are separate operands)
  floatx16 z16;
#pragma unroll
  for (int e = 0; e < 16; e++) z16[e] = 0.f;

  // stage bf16 mask addend once (2048 bf16 = 4KB = 256 chunks, 1/thread)
  async16(maskbf + b * L_ + t * 8, maskLb + t * 8);

  floatx16 o[2] = {};  // O^T acc, dg = 0,1
  float lrun = 0.f;

  for (int kv = 0; kv < 16; kv++) {
    __syncthreads();  // prev tile reads done (and first-iter mask staged)
    // linear coalesced copy: global is already fragment-ordered (1024 chunks each)
#pragma unroll
    for (int i = 0; i < 4; i++) {
      int idx = i * 256 + t;
      async16(Kp + (size_t)kv * 8192 + idx * 8, Ks + idx * 8);
    }
#pragma unroll
    for (int i = 0; i < 4; i++) {
      int idx = i * 256 + t;
      async16(VTp + (size_t)kv * 8192 + idx * 8, VTs + idx * 8);
    }
    __syncthreads();  // vmcnt drained

    // ---- S^T = mask⊗1 + K Q^T (mask enters as rank-1 MFMA, C = zero16) ----
    floatx16 s[4];
#pragma unroll
    for (int kg = 0; kg < 4; kg++) {
      union { uint32_t u[4]; short8 v; } mf;
      unsigned short mval = maskLb[kv * 128 + kg * 32 + c32];
      mf.u[0] = h ? 0u : (uint32_t)mval;
      mf.u[1] = 0; mf.u[2] = 0; mf.u[3] = 0;
      s[kg] = __builtin_amdgcn_mfma_f32_32x32x16_bf16(mf.v, onef.v, z16, 0, 0, 0);
#pragma unroll
      for (int ks = 0; ks < 4; ks++) {
        const short8 kfr = *(const short8*)(Ks + ((kg * 4 + ks) * 2 + h) * 256 + c32 * 8);
        s[kg] = __builtin_amdgcn_mfma_f32_32x32x16_bf16(kfr, qf[ks], s[kg], 0, 0, 0);
      }
    }

    // ---- softmax (fixed max 0): p = exp2(s); tree rowsum (4 chains) + lane^32 ----
    float r0 = 0.f, r1 = 0.f, r2 = 0.f, r3 = 0.f;
#pragma unroll
    for (int kg = 0; kg < 4; kg++)
#pragma unroll
      for (int q = 0; q < 4; q++) {
        float p0 = __builtin_amdgcn_exp2f(s[kg][4 * q + 0]);
        float p1 = __builtin_amdgcn_exp2f(s[kg][4 * q + 1]);
        float p2 = __builtin_amdgcn_exp2f(s[kg][4 * q + 2]);
        float p3 = __builtin_amdgcn_exp2f(s[kg][4 * q + 3]);
        s[kg][4 * q + 0] = p0; s[kg][4 * q + 1] = p1;
        s[kg][4 * q + 2] = p2; s[kg][4 * q + 3] = p3;
        r0 += p0; r1 += p1; r2 += p2; r3 += p3;
      }
    float rs = (r0 + r1) + (r2 + r3);
    rs += __shfl_xor(rs, 32);
    lrun += rs;

    // ---- P -> B-fragments (cvt_pk + permlane32_swap), O^T += VT * P^T ----
#pragma unroll
    for (int kg = 0; kg < 4; kg++) {
      uint32_t pk[8];
#pragma unroll
      for (int e = 0; e < 8; e++) pk[e] = cvtpk(s[kg][2 * e], s[kg][2 * e + 1]);
      // pk[e]: rr = e>>1, p = e&1; keys kg*32 + 8rr + 4h + 2p + {0,1}
#pragma unroll
      for (int ts = 0; ts < 2; ts++) {
        uint32_t x0 = pk[4 * ts + 0], x1 = pk[4 * ts + 1];      // rr = 2ts
        uint32_t y0 = pk[4 * ts + 2], y1 = pk[4 * ts + 3];      // rr = 2ts+1
        pl32swap(x0, y0);  // now lane h gets rr=2ts+h: x=(hs0), y=(hs1)
        pl32swap(x1, y1);
        union { uint32_t u[4]; short8 v; } pf;
        pf.u[0] = x0; pf.u[1] = x1; pf.u[2] = y0; pf.u[3] = y1;
        const int kt = kg * 2 + ts;
#pragma unroll
        for (int dg = 0; dg < 2; dg++) {
          const short8 vfr =
              *(const short8*)(VTs + ((dg * 8 + kt) * 2 + h) * 256 + c32 * 8);
          o[dg] = __builtin_amdgcn_mfma_f32_32x32x16_bf16(vfr, pf.v, o[dg], 0, 0, 0);
        }
      }
    }
  }

  // ---- epilogue (software-RNE f2bf): d = dg*32 + (e&3) + 8*(e>>2) + 4h ----
  const float inv = 1.f / lrun;
#pragma unroll
  for (int dg = 0; dg < 2; dg++)
#pragma unroll
    for (int rr = 0; rr < 4; rr++) {
      short4v ov;
#pragma unroll
      for (int jj = 0; jj < 4; jj++) ov[jj] = (short)f2bf(o[dg][rr * 4 + jj] * inv);
      int d0 = dg * 32 + rr * 8 + h * 4;
      *(short4v*)(attn_out + ((size_t)b * L_ + qrow) * C_ + hh * HD_ + d0) = ov;
    }
}

extern "C" void kernel_launch(void* const* d_in, const int* in_sizes, int n_in,
                              void* d_out, int out_size, void* d_ws, size_t ws_size,
                              hipStream_t stream) {
  const float* x = (const float*)d_in[0];
  const int* mask = (const int*)d_in[1];
  const float* Wqkv = (const float*)d_in[2];
  const float* bqkv = (const float*)d_in[3];
  const float* Wproj = (const float*)d_in[4];
  const float* bproj = (const float*)d_in[5];
  float* out = (float*)d_out;
  char* ws = (char*)d_ws;

  unsigned short* Xb = (unsigned short*)(ws);                    // 8 MB [4096][1024]
  unsigned short* WqkvT = (unsigned short*)(ws + (8u << 20));    // 6 MB [3072][1024]
  unsigned short* WprojT = (unsigned short*)(ws + (14u << 20));  // 2 MB [1024][1024]
  unsigned short* Qb = (unsigned short*)(ws + (16u << 20));      // 8 MB [32][2048][64]
  unsigned short* Kb = (unsigned short*)(ws + (24u << 20));      // 8 MB frag-order
  unsigned short* VTb = (unsigned short*)(ws + (32u << 20));     // 8 MB frag-order
  unsigned short* AOb = Xb;                                      // reuse (Xb dead after gemm1)
  unsigned short* maskbf = (unsigned short*)(ws + (40u << 20));  // 8 KB

  prep_k<<<6160, 256, 0, stream>>>(x, Xb, mask, maskbf, Wqkv, WqkvT, Wproj, WprojT);

  gemm128<1, 128><<<768, 256, 0, stream>>>(Xb, WqkvT, C_, 24, bqkv, Qb, Kb, VTb, nullptr);

  attn_k<<<B_ * H_ * (L_ / 128), 256, 0, stream>>>(Qb, Kb, VTb, maskbf, AOb);

  gemm128<2, 64><<<512, 256, 0, stream>>>(AOb, WprojT, C_, 16, bproj, nullptr, nullptr, nullptr,
                                          out);
}